// Round 9
// baseline (331.143 us; speedup 1.0000x reference)
//
#include <hip/hip_runtime.h>
#include <hip/hip_bf16.h>

#define IN_DIM   8
#define IN_CAPS  1152
#define OUT_CAPS 10
#define OUT_DIM  16
#define BATCH    512
#define CSPLIT   32
#define CCHUNK   (IN_CAPS / CSPLIT)     // 36 c per block
#define NT4      (CCHUNK / 4)           // 9 tile4 per block
#define NT4G     (IN_CAPS / 4)          // 288 global tile4
#define BT       16                     // batches per block (MFMA N)
#define NBT      (BATCH / BT)           // 32
#define SSZ      (BATCH * OUT_CAPS * OUT_DIM)   // 81920 f32
#define SROW     164                    // shorts per b-row in s_bf
#define ACCROW   168                    // f32 per b-row in sacc
#define XROW     (CCHUNK * IN_DIM + 4)  // 292 f32 per b-row in xs
#define PARTSZ   (CSPLIT * SSZ)         // 10.49 MB
#define WGSZ     ((size_t)NT4G * OUT_CAPS * 64 * 8)   // shorts per Wg buffer

typedef float  f32x4 __attribute__((ext_vector_type(4)));
typedef short  s16x8 __attribute__((ext_vector_type(8)));

static __device__ __forceinline__ short f2bs(float f) {
  __hip_bfloat16 h = __float2bfloat16(f);
  short s;
  __builtin_memcpy(&s, &h, 2);
  return s;
}

// ---- prep: pre-permute W into per-lane MFMA fragments (bf16), run once ----
// Layout: frag index idx = (t4*OUT_CAPS + o)*64 + lane ; 8 bf16 (16B) each.
__global__ __launch_bounds__(256) void prep_kernel(const float* __restrict__ W,
                                                   short* __restrict__ Wg1,
                                                   short* __restrict__ Wg2) {
  const int idx = blockIdx.x * 256 + threadIdx.x;   // 184320 total, grid exact
  const int l    = idx & 63;
  const int o    = (idx >> 6) % OUT_CAPS;
  const int t4   = idx / (OUT_CAPS * 64);
  const int b    = l & 15;
  const int g    = l >> 4;
  const int isub = 4 * (g & 1);
  const int cOff = g >> 1;
  const int c4   = t4 * 4;

  // GEMM2 A-frag: j<4: W[o, c4+cOff, d=b, isub+j] ; j>=4: same at c+2
  const float4 wva = *(const float4*)(W + (((size_t)o * IN_CAPS + c4 + cOff)     * OUT_DIM + b) * IN_DIM + isub);
  const float4 wvb = *(const float4*)(W + (((size_t)o * IN_CAPS + c4 + 2 + cOff) * OUT_DIM + b) * IN_DIM + isub);
  s16x8 w2 = {f2bs(wva.x), f2bs(wva.y), f2bs(wva.z), f2bs(wva.w),
              f2bs(wvb.x), f2bs(wvb.y), f2bs(wvb.z), f2bs(wvb.w)};
  *(s16x8*)(Wg2 + (size_t)idx * 8) = w2;

  // GEMM1 A-frag: j<4 (h=0): W[o, c4+(b>>3), d=4g+j, i=b&7]; j>=4 (h=1): c+2
  const float* w10 = W + (((size_t)o * IN_CAPS + c4 + (b >> 3))     * OUT_DIM + 4 * g) * IN_DIM + (b & 7);
  const float* w11 = W + (((size_t)o * IN_CAPS + c4 + 2 + (b >> 3)) * OUT_DIM + 4 * g) * IN_DIM + (b & 7);
  s16x8 w1 = {f2bs(w10[0]), f2bs(w10[8]), f2bs(w10[16]), f2bs(w10[24]),
              f2bs(w11[0]), f2bs(w11[8]), f2bs(w11[16]), f2bs(w11[24])};
  *(s16x8*)(Wg1 + (size_t)idx * 8) = w1;
}

// MODE 0: cw = 0.1 -> part ; MODE 1: logits from sA -> part ; MODE 2: sA+sB -> part
// MFMA 16x16x32 frag k-map (two 16x16x16 halves), HW-validated R5-R8:
//   elem j<4 : k = 4*(lane>>4)+j ; elem j>=4 : k = 16+4*(lane>>4)+(j-4)
//   A row m = lane&15 ; B col n = lane&15 ; D: col = lane&15, row = 4*(lane>>4)+reg
template<int MODE>
__global__ __launch_bounds__(256, 4) void sweep_kernel(
    const float* __restrict__ x, const short* __restrict__ Wg1,
    const short* __restrict__ Wg2,
    const float* __restrict__ sA, const float* __restrict__ sB,
    float* __restrict__ part) {
  __shared__ short s_bf[16 * SROW];      // 5.2 KB  s[b][o*16+d] bf16
  __shared__ float xs[16 * XROW];        // 18.7 KB x[b][cl*8+i]
  __shared__ float sacc[16 * ACCROW];    // 10.8 KB cross-wave partial

  const int tid  = threadIdx.x;
  const int wid  = tid >> 6;
  const int lane = tid & 63;
  const int b    = lane & 15;
  const int g    = lane >> 4;
  const int bt   = blockIdx.x / CSPLIT;
  const int ch   = blockIdx.x % CSPLIT;  // xcd = ch%8 round-robin -> Wg L2 locality
  const int c0   = ch * CCHUNK;
  const int bb0  = bt * BT;

  for (int idx = tid; idx < 16 * 72; idx += 256) {
    int bb = idx / 72, j = idx % 72;
    *(float4*)(xs + bb * XROW + j * 4) =
        *(const float4*)(x + ((size_t)(bb0 + bb) * IN_CAPS + c0) * IN_DIM + j * 4);
  }
  if (MODE != 0) {
    for (int k = tid; k < 16 * 160; k += 256) {
      int bb = k / 160, od = k % 160;
      float v = sA[(size_t)(bb0 + bb) * 160 + od];
      if (MODE == 2) v += sB[(size_t)(bb0 + bb) * 160 + od];
      s_bf[bb * SROW + od] = f2bs(v);
    }
  }
  for (int k = tid; k < 16 * ACCROW; k += 256) sacc[k] = 0.f;
  __syncthreads();

  f32x4 acc[OUT_CAPS];
  #pragma unroll
  for (int o = 0; o < OUT_CAPS; ++o) acc[o] = (f32x4){0.f, 0.f, 0.f, 0.f};

  const int isub = 4 * (g & 1);
  const s16x8* W1f = (const s16x8*)Wg1;
  const s16x8* W2f = (const s16x8*)Wg2;

  for (int t = wid; t < NT4; t += 4) {
    const int t4g = ch * NT4 + t;
    const size_t fbase = (size_t)t4g * (OUT_CAPS * 64) + lane;
    const int clA = t * 4 + (g >> 1);
    const int clB = clA + 2;
    const float4 xq0 = *(const float4*)(xs + b * XROW + clA * IN_DIM + isub);
    const float4 xq1 = *(const float4*)(xs + b * XROW + clB * IN_DIM + isub);

    float lg[2][OUT_CAPS];

    if (MODE != 0) {
      #pragma unroll
      for (int o = 0; o < OUT_CAPS; ++o) {
        ushort4 sv = *(const ushort4*)&s_bf[b * SROW + o * 16 + 4 * g];
        s16x8 sb = {(short)sv.x, (short)sv.y, (short)sv.z, (short)sv.w, 0, 0, 0, 0};
        s16x8 a1 = W1f[fbase + (size_t)o * 64];
        f32x4 zz = (f32x4){0.f, 0.f, 0.f, 0.f};
        f32x4 d0 = __builtin_amdgcn_mfma_f32_16x16x32_bf16(a1, sb, zz, 0, 0, 0);
        // h=1 half lives in elems 4..7; sb's k>=16 are zero so tail garbage is harmless
        s16x8 a1h = __builtin_shufflevector(a1, a1, 4, 5, 6, 7, 4, 5, 6, 7);
        f32x4 d1 = __builtin_amdgcn_mfma_f32_16x16x32_bf16(a1h, sb, zz, 0, 0, 0);
        float p0 = d0[0] * xq0.x + d0[1] * xq0.y + d0[2] * xq0.z + d0[3] * xq0.w;
        float p1 = d1[0] * xq1.x + d1[1] * xq1.y + d1[2] * xq1.z + d1[3] * xq1.w;
        p0 += __shfl_xor(p0, 16);          // partner g^1 holds the other 4 i's
        p1 += __shfl_xor(p1, 16);
        lg[0][o] = p0;
        lg[1][o] = p1;
      }
      #pragma unroll
      for (int h = 0; h < 2; ++h) {
        float m = lg[h][0];
        #pragma unroll
        for (int o = 1; o < OUT_CAPS; ++o) m = fmaxf(m, lg[h][o]);
        float sum = 0.f;
        #pragma unroll
        for (int o = 0; o < OUT_CAPS; ++o) { lg[h][o] = __expf(lg[h][o] - m); sum += lg[h][o]; }
        float inv = 1.f / sum;
        #pragma unroll
        for (int o = 0; o < OUT_CAPS; ++o) lg[h][o] *= inv;
      }
    }

    #pragma unroll
    for (int o = 0; o < OUT_CAPS; ++o) {
      const float cwA = (MODE == 0) ? 0.1f : lg[0][o];
      const float cwB = (MODE == 0) ? 0.1f : lg[1][o];
      s16x8 z8 = {f2bs(cwA * xq0.x), f2bs(cwA * xq0.y), f2bs(cwA * xq0.z), f2bs(cwA * xq0.w),
                  f2bs(cwB * xq1.x), f2bs(cwB * xq1.y), f2bs(cwB * xq1.z), f2bs(cwB * xq1.w)};
      s16x8 a2 = W2f[fbase + (size_t)o * 64];
      acc[o] = __builtin_amdgcn_mfma_f32_16x16x32_bf16(a2, z8, acc[o], 0, 0, 0);
    }
  }

  {
    float* sa = &sacc[b * ACCROW];
    #pragma unroll
    for (int o = 0; o < OUT_CAPS; ++o) {
      #pragma unroll
      for (int r = 0; r < 4; ++r) atomicAdd(&sa[o * 16 + 4 * g + r], acc[o][r]);
    }
  }
  __syncthreads();

  {
    float4* dst = (float4*)(part + ((size_t)ch * BATCH + bb0) * 160);
    for (int k = tid; k < 640; k += 256) {
      int bb = k / 40, q = k % 40;
      dst[k] = *(const float4*)(sacc + bb * ACCROW + q * 4);
    }
  }
}

__global__ __launch_bounds__(256) void reduce_kernel(
    const float* __restrict__ part, float* __restrict__ dst) {
  const int i = blockIdx.x * 256 + threadIdx.x;      // float4 index, 20480 total
  const float4* p4 = (const float4*)part;
  float4 s = p4[i];
  #pragma unroll
  for (int ch = 1; ch < CSPLIT; ++ch) {
    float4 a = p4[(size_t)ch * (SSZ / 4) + i];
    s.x += a.x; s.y += a.y; s.z += a.z; s.w += a.w;
  }
  ((float4*)dst)[i] = s;
}

extern "C" void kernel_launch(void* const* d_in, const int* in_sizes, int n_in,
                              void* d_out, int out_size, void* d_ws, size_t ws_size,
                              hipStream_t stream) {
  const float* x = (const float*)d_in[0];
  const float* W = (const float*)d_in[1];
  float* out  = (float*)d_out;
  float* part = (float*)d_ws;                 // PARTSZ f32
  float* wsA  = part + PARTSZ;                // s1
  float* wsB  = wsA + SSZ;                    // s2
  short* Wg1  = (short*)(wsB + SSZ);          // WGSZ shorts
  short* Wg2  = Wg1 + WGSZ;                   // WGSZ shorts  (total ws ~17.0 MB)
  const int GRID = NBT * CSPLIT;              // 1024

  prep_kernel<<<(NT4G * OUT_CAPS * 64) / 256, 256, 0, stream>>>(W, Wg1, Wg2);
  sweep_kernel<0><<<GRID, 256, 0, stream>>>(x, Wg1, Wg2, wsA, wsB, part);
  reduce_kernel<<<SSZ / 4 / 256, 256, 0, stream>>>(part, wsA);     // wsA = s1
  sweep_kernel<1><<<GRID, 256, 0, stream>>>(x, Wg1, Wg2, wsA, wsB, part);
  reduce_kernel<<<SSZ / 4 / 256, 256, 0, stream>>>(part, wsB);     // wsB = s2
  sweep_kernel<2><<<GRID, 256, 0, stream>>>(x, Wg1, Wg2, wsA, wsB, part);
  reduce_kernel<<<SSZ / 4 / 256, 256, 0, stream>>>(part, out);     // out = v
}